// Round 10
// baseline (79.973 us; speedup 1.0000x reference)
//
#include <hip/hip_runtime.h>

// GraphConvolutionDiagLayer: out[dst[e]] += ew[e] * (x[src[e]] * W)
// N=10000, E=640000, F=128, fp32.
//
// Round 10 (from round-9's 46.4us):
//   D1 memset:      zero g_cnt[NB]+spill_cnt (1KB).
//   D2 conv_sort1:  TILE=1024 (625 sort blocks, was 313 -> kills the 2x
//                   tail imbalance). Convert part unchanged (uint4 bf16x2).
//   D3 bucket:      1024 threads (4 waves/SIMD, was 2); node segments
//                   ZERO-PADDED to x16 records in LDS (no scalar tail);
//                   row loads as uint2 = TWO records per VMEM instruction
//                   (lane halves handle even/odd records; __shfl_xor(32)
//                   combine; each half stores one 256B half-row).
//  Spill list keeps correctness independent of cap; fallback if ws/N bad.

#define F_DIM 128
#define NB 256
#define TILE 1024
#define SPILL_CAP 8192
#define R_MAX 64

__device__ __forceinline__ unsigned f2bf_bits(float f)
{
    unsigned u = __float_as_uint(f);
    return (u + 0x7FFFu + ((u >> 16) & 1u)) >> 16;   // RNE to bf16
}

__global__ void __launch_bounds__(256)
conv_sort1_kernel(const float* __restrict__ x, const float* __restrict__ W,
                  unsigned* __restrict__ xb,
                  const int* __restrict__ src, const int* __restrict__ dst,
                  const float* __restrict__ ew,
                  int* __restrict__ g_cnt, int* __restrict__ spill_cnt,
                  int4* __restrict__ spill, uint2* __restrict__ segs,
                  int NU4, int cgrid, int E, unsigned M, int R, int cap)
{
    __shared__ unsigned reo_lo[TILE];
    __shared__ unsigned reo_hi[TILE];
    __shared__ int hist[NB], scn[NB], gbase[NB], wsum[4];

    int tid = threadIdx.x;

    if ((int)blockIdx.x < cgrid) {
        // ---------------- convert part ----------------
        int t = blockIdx.x * 256 + tid;
        if (t < NU4) {
            int n = t >> 4, jq = t & 15;
            const float4* xr = (const float4*)(x + (size_t)n * F_DIM + jq * 4);
            float4 a  = xr[0];
            float4 bb = xr[16];                 // +64 floats
            const float4* wr = (const float4*)(W + jq * 4);
            float4 wa = wr[0], wb = wr[16];
            uint4 o;
            o.x = f2bf_bits(a.x * wa.x) | (f2bf_bits(bb.x * wb.x) << 16);
            o.y = f2bf_bits(a.y * wa.y) | (f2bf_bits(bb.y * wb.y) << 16);
            o.z = f2bf_bits(a.z * wa.z) | (f2bf_bits(bb.z * wb.z) << 16);
            o.w = f2bf_bits(a.w * wa.w) | (f2bf_bits(bb.w * wb.w) << 16);
            *(uint4*)(xb + (size_t)n * 64 + jq * 4) = o;
        }
        return;
    }

    // ---------------- sort1 part ----------------
    int tile0 = ((int)blockIdx.x - cgrid) * TILE;
    int tcnt = E - tile0; if (tcnt > TILE) tcnt = TILE;

    if (tid < NB) hist[tid] = 0;
    __syncthreads();

    int b_k[4], rank_k[4]; unsigned lo_k[4], w_k[4];
    #pragma unroll
    for (int k = 0; k < 4; ++k) {
        int e = tile0 + k * 256 + tid;
        b_k[k] = -1; rank_k[k] = 0; lo_k[k] = 0; w_k[k] = 0;
        if (e < E) {
            int d = dst[e];
            int b = (int)__umulhi((unsigned)d, M);     // d / R (exact)
            int dl = d - b * R;
            b_k[k]    = b;
            lo_k[k]   = ((unsigned)src[e] & 0x3FFFu) | ((unsigned)dl << 14)
                      | ((unsigned)b << 21);
            w_k[k]    = __float_as_uint(ew[e]);
            rank_k[k] = atomicAdd(&hist[b], 1);        // LDS int atomic
        }
    }
    __syncthreads();

    // wave-shuffle inclusive scan over NB=256 (4 waves, 2 barriers)
    {
        int lane6 = tid & 63, wv = tid >> 6;
        int v = hist[tid];
        #pragma unroll
        for (int d = 1; d < 64; d <<= 1) {
            int t2 = __shfl_up(v, d);
            if (lane6 >= d) v += t2;
        }
        if (lane6 == 63) wsum[wv] = v;
        __syncthreads();
        int woff = 0;
        #pragma unroll
        for (int i2 = 0; i2 < 4; ++i2) if (i2 < wv) woff += wsum[i2];
        scn[tid] = v + woff;                            // inclusive scan
        __syncthreads();
    }

    #pragma unroll
    for (int k = 0; k < 4; ++k) {
        if (b_k[k] >= 0) {
            int b = b_k[k];
            int pos = (scn[b] - hist[b]) + rank_k[k];   // excl offset + rank
            reo_lo[pos] = lo_k[k];
            reo_hi[pos] = w_k[k];
        }
    }
    if (tid < NB)
        gbase[tid] = hist[tid] ? atomicAdd(&g_cnt[tid], hist[tid]) : 0;
    __syncthreads();

    for (int p = tid; p < tcnt; p += 256) {
        unsigned lo = reo_lo[p];
        int b = (int)(lo >> 21);
        int slot = gbase[b] + (p - (scn[b] - hist[b]));
        if (slot < cap) {
            segs[(size_t)b * cap + slot] = make_uint2(lo, reo_hi[p]);
        } else {
            int sp = atomicAdd(spill_cnt, 1);
            if (sp < SPILL_CAP) {
                int dl = (int)((lo >> 14) & 0x7Fu);
                spill[sp] = make_int4(b * R + dl, (int)(lo & 0x3FFFu),
                                      (int)reo_hi[p], 0);
            }
        }
    }
}

// One block per bucket, 1024 threads: register-staged counting sort to node
// order in LDS (segments zero-padded to x16), then 16-wave gather; row loads
// are uint2 (2 records per VMEM instr), __shfl_xor(32) combine.
__global__ void __launch_bounds__(1024)
bucket_kernel(const unsigned* __restrict__ xb, const uint2* __restrict__ segs,
              const int* __restrict__ g_cnt, const int* __restrict__ spill_cnt,
              const int4* __restrict__ spill, float* __restrict__ out,
              int N, int R, int cap, int cap2)
{
    extern __shared__ unsigned char smem[];
    float*          w_l = (float*)smem;                       // [cap2]
    unsigned short* s_l = (unsigned short*)(w_l + cap2);      // [cap2]
    __shared__ int hist2[R_MAX], pexcl[R_MAX], cur[R_MAX];

    int b   = blockIdx.x;
    int tid = threadIdx.x;
    int rows = N - b * R; if (rows > R) rows = R;
    if (rows <= 0) return;

    if (tid < R_MAX) hist2[tid] = 0;
    __syncthreads();

    int cnt = g_cnt[b]; if (cnt > cap) cnt = cap;
    const uint2* seg = segs + (size_t)b * cap;

    unsigned lo_r[4], hi_r[4];
    #pragma unroll
    for (int k = 0; k < 4; ++k) {
        int r = tid + k * 1024;
        lo_r[k] = 0xFFFFFFFFu; hi_r[k] = 0;
        if (r < cnt) {
            uint2 q = seg[r];
            lo_r[k] = q.x; hi_r[k] = q.y;
            atomicAdd(&hist2[(q.x >> 14) & 0x7Fu], 1);
        }
    }
    __syncthreads();

    if (tid < 64) {
        int h = (tid < rows) ? hist2[tid] : 0;
        int p = (h + 15) & ~15;               // pad each segment to x16
        int v = p;
        #pragma unroll
        for (int d = 1; d < 64; d <<= 1) {
            int t2 = __shfl_up(v, d);
            if (tid >= d) v += t2;
        }
        int excl = v - p;
        if (tid < rows) { pexcl[tid] = excl; cur[tid] = excl; }
    }
    __syncthreads();

    #pragma unroll
    for (int k = 0; k < 4; ++k) {
        if (lo_r[k] != 0xFFFFFFFFu) {
            int dl = (int)((lo_r[k] >> 14) & 0x7Fu);
            int pos = atomicAdd(&cur[dl], 1);  // LDS int atomic
            s_l[pos] = (unsigned short)(lo_r[k] & 0x3FFFu);
            w_l[pos] = __uint_as_float(hi_r[k]);
        }
    }
    __syncthreads();

    // zero-fill pad region (w=0, src=0 -> contributes nothing)
    if (tid < rows) {
        int h = hist2[tid];
        int hp = (h + 15) & ~15;
        int base = pexcl[tid];
        for (int p = base + h; p < base + hp; ++p) {
            s_l[p] = 0; w_l[p] = 0.f;
        }
    }
    __syncthreads();

    // ---------------- gather phase ----------------
    int wid = tid >> 6, lane = tid & 63;
    int l32 = lane & 31, h = lane >> 5;       // half: 0 = even recs, 1 = odd
    const uint2* xb2 = (const uint2*)xb;
    int sc = *spill_cnt; if (sc > SPILL_CAP) sc = SPILL_CAP;

    for (int dl = wid; dl < rows; dl += 16) {
        int hp   = (hist2[dl] + 15) & ~15;
        int base = pexcl[dl];
        const unsigned short* ps = s_l + base;
        const float*          pw = w_l + base;

        float s0 = 0.f, s1 = 0.f, s2 = 0.f, s3 = 0.f;
        for (int i = 0; i < hp; i += 16) {
            uint4 sa = *(const uint4*)(ps + i);
            uint4 sb = *(const uint4*)(ps + i + 8);
            float4 wa = *(const float4*)(pw + i);
            float4 wb = *(const float4*)(pw + i + 4);
            float4 wc = *(const float4*)(pw + i + 8);
            float4 wd = *(const float4*)(pw + i + 12);
            unsigned sv[16] = {sa.x & 0xFFFFu, sa.x >> 16, sa.y & 0xFFFFu, sa.y >> 16,
                               sa.z & 0xFFFFu, sa.z >> 16, sa.w & 0xFFFFu, sa.w >> 16,
                               sb.x & 0xFFFFu, sb.x >> 16, sb.y & 0xFFFFu, sb.y >> 16,
                               sb.z & 0xFFFFu, sb.z >> 16, sb.w & 0xFFFFu, sb.w >> 16};
            // this lane-half's row for pair k: record 2k+h
            uint2 rv[8];
            #pragma unroll
            for (int k = 0; k < 8; ++k) {
                unsigned srow = h ? sv[2 * k + 1] : sv[2 * k];
                rv[k] = xb2[(size_t)srow * 32 + l32];
            }
            float we[8] = {wa.x, wa.z, wb.x, wb.z, wc.x, wc.z, wd.x, wd.z};
            float wo[8] = {wa.y, wa.w, wb.y, wb.w, wc.y, wc.w, wd.y, wd.w};
            #pragma unroll
            for (int k = 0; k < 8; ++k) {
                float w = h ? wo[k] : we[k];
                uint2 q = rv[k];
                s0 += w * __uint_as_float(q.x << 16);
                s2 += w * __uint_as_float(q.x & 0xFFFF0000u);
                s1 += w * __uint_as_float(q.y << 16);
                s3 += w * __uint_as_float(q.y & 0xFFFF0000u);
            }
        }

        // combine even/odd halves: lane l <-> lane l^32
        s0 += __shfl_xor(s0, 32);
        s1 += __shfl_xor(s1, 32);
        s2 += __shfl_xor(s2, 32);
        s3 += __shfl_xor(s3, 32);

        int n = b * R + dl;

        // spill fold-in (normally 0; both halves compute identical values)
        for (int t = 0; t < sc; ++t) {
            int4 sp = spill[t];
            if (sp.x == n) {
                uint2 q = xb2[(size_t)sp.y * 32 + l32];
                float w = __int_as_float(sp.z);
                s0 += w * __uint_as_float(q.x << 16);
                s2 += w * __uint_as_float(q.x & 0xFFFF0000u);
                s1 += w * __uint_as_float(q.y << 16);
                s3 += w * __uint_as_float(q.y & 0xFFFF0000u);
            }
        }

        // lane half 0 stores cols [2*l32, 2*l32+1]; half 1 stores +64
        float2 o = h ? make_float2(s2, s3) : make_float2(s0, s1);
        int col = h * 64 + 2 * l32;
        *(float2*)(out + (size_t)n * F_DIM + col) = o;
    }
}

// ---- fallback: direct fp32 atomic scatter ----
__global__ void __launch_bounds__(256)
fallback_scatter(const float* __restrict__ x, const float* __restrict__ W,
                 const float* __restrict__ ew, const int* __restrict__ src,
                 const int* __restrict__ dst, float* __restrict__ out, int E)
{
    int t = blockIdx.x * 256 + threadIdx.x;
    int e = t >> 5;
    if (e >= E) return;
    int f4 = t & 31;
    int   s = src[e];
    int   d = dst[e];
    float w = ew[e];
    float4 xv = reinterpret_cast<const float4*>(x)[s * 32 + f4];
    float4 wv = reinterpret_cast<const float4*>(W)[f4];
    float* o = out + d * F_DIM + f4 * 4;
    unsafeAtomicAdd(o + 0, xv.x * wv.x * w);
    unsafeAtomicAdd(o + 1, xv.y * wv.y * w);
    unsafeAtomicAdd(o + 2, xv.z * wv.z * w);
    unsafeAtomicAdd(o + 3, xv.w * wv.w * w);
}

extern "C" void kernel_launch(void* const* d_in, const int* in_sizes, int n_in,
                              void* d_out, int out_size, void* d_ws, size_t ws_size,
                              hipStream_t stream)
{
    const float* x   = (const float*)d_in[0];
    const float* W   = (const float*)d_in[1];
    const float* ew  = (const float*)d_in[2];
    const int*   src = (const int*)d_in[3];
    const int*   dst = (const int*)d_in[4];
    float*       out = (float*)d_out;

    const int E  = in_sizes[2];
    const int N  = out_size / F_DIM;
    const int NU = N * 64;

    const int R = (N + NB - 1) / NB;                    // nodes per bucket
    int cap = (3 * E / (2 * NB) + 256) & ~255;          // ~1.5x mean, rounded
    if (cap < 512) cap = 512;
    const int cap2 = cap + 16 * R_MAX;                  // padded LDS cap
    const size_t smem_bytes = (size_t)cap2 * 6;         // f32 w + u16 src

    // ws layout (uint units): xb[NU] | segs[NB*cap*2] | g_cnt[NB]
    //   | spill_cnt[1] | align4 | spill[SPILL_CAP*4]
    size_t xb_off        = 0;
    size_t segs_off      = xb_off + (size_t)NU;
    size_t cnt_off       = segs_off + (size_t)NB * cap * 2;
    size_t spill_cnt_off = cnt_off + NB;
    size_t spill_off     = (spill_cnt_off + 1 + 3) & ~(size_t)3;
    size_t need          = (spill_off + (size_t)SPILL_CAP * 4) * 4;

    if (ws_size >= need && N >= 1 && N <= 16384 && R <= R_MAX &&
        cap <= 4096 && smem_bytes <= 64 * 1024) {
        unsigned* xb        = (unsigned*)d_ws + xb_off;
        uint2*    segs      = (uint2*)((unsigned*)d_ws + segs_off);
        int*      g_cnt     = (int*)d_ws + cnt_off;
        int*      spill_cnt = (int*)d_ws + spill_cnt_off;
        int4*     spill     = (int4*)((unsigned*)d_ws + spill_off);

        const unsigned M = (unsigned)((0x100000000ULL + R - 1) / (unsigned)R);

        int NU4    = NU / 4;
        int cgrid  = (NU4 + 255) / 256;
        int s1grid = (E + TILE - 1) / TILE;
        int bgrid  = (N + R - 1) / R;

        hipMemsetAsync(g_cnt, 0, (size_t)(NB + 1) * sizeof(int), stream);
        conv_sort1_kernel<<<cgrid + s1grid, 256, 0, stream>>>(
            x, W, xb, src, dst, ew, g_cnt, spill_cnt, spill, segs,
            NU4, cgrid, E, M, R, cap);
        bucket_kernel<<<bgrid, 1024, smem_bytes, stream>>>(
            xb, segs, g_cnt, spill_cnt, spill, out, N, R, cap, cap2);
    } else {
        hipMemsetAsync(out, 0, (size_t)out_size * sizeof(float), stream);
        long long tt = (long long)E * 32;
        int grid = (int)((tt + 255) / 256);
        if (grid < 1) grid = 1;
        fallback_scatter<<<grid, 256, 0, stream>>>(x, W, ew, src, dst, out, E);
    }
}

// Round 11
// 47.610 us; speedup vs baseline: 1.6797x; 1.6797x over previous
//
#include <hip/hip_runtime.h>

// GraphConvolutionDiagLayer: out[dst[e]] += ew[e] * (x[src[e]] * W)
// N=10000, E=640000, F=128, fp32.
//
// Round 11 (post-mortem of round-10's 80us regression):
//  bucket_kernel's lane-half select (h ? sv[2k+1] : sv[2k]) became a
//  RUNTIME-indexed register array -> scratch (VGPR_Count 28, WRITE_SIZE
//  157MB of scratch writebacks = the whole regression; rule #20).
//  Revert gather to round-9's fully-static dword row loads; KEEP the x16
//  zero-padded segments (no scalar tail), KEEP 1024 threads (4 waves/SIMD),
//  KEEP TILE=1024 sort1.
//   D1 memset:     zero g_cnt[NB]+spill_cnt (1KB).
//   D2 conv_sort1: convert xb=pack2(bf16(x*W)) (uint4) ++ 1024-edge tiles ->
//                  NB=256 dst-range buckets (LDS hist + shuffle scan +
//                  reorder, 1 global atomic per tile*bucket, 8B rec stores).
//   D3 bucket:     one block/bucket, 1024 thr: reg-staged counting sort to
//                  node order in LDS (pad x16, w=0 filler), 16-wave gather,
//                  16 static dword row loads per batch, register acc,
//                  dense single write.
//  Spill list keeps correctness independent of cap; fallback if ws/N bad.

#define F_DIM 128
#define NB 256
#define TILE 1024
#define SPILL_CAP 8192
#define R_MAX 64

__device__ __forceinline__ unsigned f2bf_bits(float f)
{
    unsigned u = __float_as_uint(f);
    return (u + 0x7FFFu + ((u >> 16) & 1u)) >> 16;   // RNE to bf16
}

__global__ void __launch_bounds__(256)
conv_sort1_kernel(const float* __restrict__ x, const float* __restrict__ W,
                  unsigned* __restrict__ xb,
                  const int* __restrict__ src, const int* __restrict__ dst,
                  const float* __restrict__ ew,
                  int* __restrict__ g_cnt, int* __restrict__ spill_cnt,
                  int4* __restrict__ spill, uint2* __restrict__ segs,
                  int NU4, int cgrid, int E, unsigned M, int R, int cap)
{
    __shared__ unsigned reo_lo[TILE];
    __shared__ unsigned reo_hi[TILE];
    __shared__ int hist[NB], scn[NB], gbase[NB], wsum[4];

    int tid = threadIdx.x;

    if ((int)blockIdx.x < cgrid) {
        // ---------------- convert part ----------------
        int t = blockIdx.x * 256 + tid;
        if (t < NU4) {
            int n = t >> 4, jq = t & 15;
            const float4* xr = (const float4*)(x + (size_t)n * F_DIM + jq * 4);
            float4 a  = xr[0];
            float4 bb = xr[16];                 // +64 floats
            const float4* wr = (const float4*)(W + jq * 4);
            float4 wa = wr[0], wb = wr[16];
            uint4 o;
            o.x = f2bf_bits(a.x * wa.x) | (f2bf_bits(bb.x * wb.x) << 16);
            o.y = f2bf_bits(a.y * wa.y) | (f2bf_bits(bb.y * wb.y) << 16);
            o.z = f2bf_bits(a.z * wa.z) | (f2bf_bits(bb.z * wb.z) << 16);
            o.w = f2bf_bits(a.w * wa.w) | (f2bf_bits(bb.w * wb.w) << 16);
            *(uint4*)(xb + (size_t)n * 64 + jq * 4) = o;
        }
        return;
    }

    // ---------------- sort1 part ----------------
    int tile0 = ((int)blockIdx.x - cgrid) * TILE;
    int tcnt = E - tile0; if (tcnt > TILE) tcnt = TILE;

    if (tid < NB) hist[tid] = 0;
    __syncthreads();

    int b_k[4], rank_k[4]; unsigned lo_k[4], w_k[4];
    #pragma unroll
    for (int k = 0; k < 4; ++k) {
        int e = tile0 + k * 256 + tid;
        b_k[k] = -1; rank_k[k] = 0; lo_k[k] = 0; w_k[k] = 0;
        if (e < E) {
            int d = dst[e];
            int b = (int)__umulhi((unsigned)d, M);     // d / R (exact)
            int dl = d - b * R;
            b_k[k]    = b;
            lo_k[k]   = ((unsigned)src[e] & 0x3FFFu) | ((unsigned)dl << 14)
                      | ((unsigned)b << 21);
            w_k[k]    = __float_as_uint(ew[e]);
            rank_k[k] = atomicAdd(&hist[b], 1);        // LDS int atomic
        }
    }
    __syncthreads();

    // wave-shuffle inclusive scan over NB=256 (4 waves, 2 barriers)
    {
        int lane6 = tid & 63, wv = tid >> 6;
        int v = hist[tid];
        #pragma unroll
        for (int d = 1; d < 64; d <<= 1) {
            int t2 = __shfl_up(v, d);
            if (lane6 >= d) v += t2;
        }
        if (lane6 == 63) wsum[wv] = v;
        __syncthreads();
        int woff = 0;
        #pragma unroll
        for (int i2 = 0; i2 < 4; ++i2) if (i2 < wv) woff += wsum[i2];
        scn[tid] = v + woff;                            // inclusive scan
        __syncthreads();
    }

    #pragma unroll
    for (int k = 0; k < 4; ++k) {
        if (b_k[k] >= 0) {
            int b = b_k[k];
            int pos = (scn[b] - hist[b]) + rank_k[k];   // excl offset + rank
            reo_lo[pos] = lo_k[k];
            reo_hi[pos] = w_k[k];
        }
    }
    if (tid < NB)
        gbase[tid] = hist[tid] ? atomicAdd(&g_cnt[tid], hist[tid]) : 0;
    __syncthreads();

    for (int p = tid; p < tcnt; p += 256) {
        unsigned lo = reo_lo[p];
        int b = (int)(lo >> 21);
        int slot = gbase[b] + (p - (scn[b] - hist[b]));
        if (slot < cap) {
            segs[(size_t)b * cap + slot] = make_uint2(lo, reo_hi[p]);
        } else {
            int sp = atomicAdd(spill_cnt, 1);
            if (sp < SPILL_CAP) {
                int dl = (int)((lo >> 14) & 0x7Fu);
                spill[sp] = make_int4(b * R + dl, (int)(lo & 0x3FFFu),
                                      (int)reo_hi[p], 0);
            }
        }
    }
}

// One block per bucket, 1024 threads: register-staged counting sort to node
// order in LDS (segments zero-padded to x16), then 16-wave gather with fully
// STATIC register indexing (rule #20) and dword row loads.
__global__ void __launch_bounds__(1024)
bucket_kernel(const unsigned* __restrict__ xb, const uint2* __restrict__ segs,
              const int* __restrict__ g_cnt, const int* __restrict__ spill_cnt,
              const int4* __restrict__ spill, float* __restrict__ out,
              int N, int R, int cap, int cap2)
{
    extern __shared__ unsigned char smem[];
    float*          w_l = (float*)smem;                       // [cap2]
    unsigned short* s_l = (unsigned short*)(w_l + cap2);      // [cap2]
    __shared__ int hist2[R_MAX], pexcl[R_MAX], cur[R_MAX];

    int b   = blockIdx.x;
    int tid = threadIdx.x;
    int rows = N - b * R; if (rows > R) rows = R;
    if (rows <= 0) return;

    if (tid < R_MAX) hist2[tid] = 0;
    __syncthreads();

    int cnt = g_cnt[b]; if (cnt > cap) cnt = cap;
    const uint2* seg = segs + (size_t)b * cap;

    unsigned lo_r[4], hi_r[4];
    #pragma unroll
    for (int k = 0; k < 4; ++k) {
        int r = tid + k * 1024;
        lo_r[k] = 0xFFFFFFFFu; hi_r[k] = 0;
        if (r < cnt) {
            uint2 q = seg[r];
            lo_r[k] = q.x; hi_r[k] = q.y;
            atomicAdd(&hist2[(q.x >> 14) & 0x7Fu], 1);
        }
    }
    __syncthreads();

    if (tid < 64) {
        int h = (tid < rows) ? hist2[tid] : 0;
        int p = (h + 15) & ~15;               // pad each segment to x16
        int v = p;
        #pragma unroll
        for (int d = 1; d < 64; d <<= 1) {
            int t2 = __shfl_up(v, d);
            if (tid >= d) v += t2;
        }
        int excl = v - p;
        if (tid < rows) { pexcl[tid] = excl; cur[tid] = excl; }
    }
    __syncthreads();

    #pragma unroll
    for (int k = 0; k < 4; ++k) {
        if (lo_r[k] != 0xFFFFFFFFu) {
            int dl = (int)((lo_r[k] >> 14) & 0x7Fu);
            int pos = atomicAdd(&cur[dl], 1);  // LDS int atomic
            s_l[pos] = (unsigned short)(lo_r[k] & 0x3FFFu);
            w_l[pos] = __uint_as_float(hi_r[k]);
        }
    }
    __syncthreads();

    // zero-fill pad region (w=0, src=0 -> contributes nothing)
    if (tid < rows) {
        int h = hist2[tid];
        int hp = (h + 15) & ~15;
        int base = pexcl[tid];
        for (int p = base + h; p < base + hp; ++p) {
            s_l[p] = 0; w_l[p] = 0.f;
        }
    }
    __syncthreads();

    // ---------------- gather phase ----------------
    int wid = tid >> 6, lane = tid & 63;
    int sc = *spill_cnt; if (sc > SPILL_CAP) sc = SPILL_CAP;

    for (int dl = wid; dl < rows; dl += 16) {
        int hp   = (hist2[dl] + 15) & ~15;
        int base = pexcl[dl];
        const unsigned short* ps = s_l + base;
        const float*          pw = w_l + base;

        float ax = 0.f, ay = 0.f;
        for (int i = 0; i < hp; i += 16) {
            uint4 sa = *(const uint4*)(ps + i);
            uint4 sb = *(const uint4*)(ps + i + 8);
            float4 wa = *(const float4*)(pw + i);
            float4 wb = *(const float4*)(pw + i + 4);
            float4 wc = *(const float4*)(pw + i + 8);
            float4 wd = *(const float4*)(pw + i + 12);
            unsigned sv[16] = {sa.x & 0xFFFFu, sa.x >> 16, sa.y & 0xFFFFu, sa.y >> 16,
                               sa.z & 0xFFFFu, sa.z >> 16, sa.w & 0xFFFFu, sa.w >> 16,
                               sb.x & 0xFFFFu, sb.x >> 16, sb.y & 0xFFFFu, sb.y >> 16,
                               sb.z & 0xFFFFu, sb.z >> 16, sb.w & 0xFFFFu, sb.w >> 16};
            float wv[16] = {wa.x, wa.y, wa.z, wa.w, wb.x, wb.y, wb.z, wb.w,
                            wc.x, wc.y, wc.z, wc.w, wd.x, wd.y, wd.z, wd.w};
            unsigned rv[16];
            #pragma unroll
            for (int k = 0; k < 16; ++k)
                rv[k] = xb[(size_t)sv[k] * 64 + lane];
            #pragma unroll
            for (int k = 0; k < 16; ++k) {
                ax += wv[k] * __uint_as_float(rv[k] << 16);
                ay += wv[k] * __uint_as_float(rv[k] & 0xFFFF0000u);
            }
        }

        int n = b * R + dl;
        for (int t = 0; t < sc; ++t) {          // spill fold-in (normally 0)
            int4 sp = spill[t];
            if (sp.x == n) {
                unsigned rv = xb[(size_t)sp.y * 64 + lane];
                float w = __int_as_float(sp.z);
                ax += w * __uint_as_float(rv << 16);
                ay += w * __uint_as_float(rv & 0xFFFF0000u);
            }
        }

        out[(size_t)n * F_DIM + lane]      = ax;
        out[(size_t)n * F_DIM + 64 + lane] = ay;
    }
}

// ---- fallback: direct fp32 atomic scatter ----
__global__ void __launch_bounds__(256)
fallback_scatter(const float* __restrict__ x, const float* __restrict__ W,
                 const float* __restrict__ ew, const int* __restrict__ src,
                 const int* __restrict__ dst, float* __restrict__ out, int E)
{
    int t = blockIdx.x * 256 + threadIdx.x;
    int e = t >> 5;
    if (e >= E) return;
    int f4 = t & 31;
    int   s = src[e];
    int   d = dst[e];
    float w = ew[e];
    float4 xv = reinterpret_cast<const float4*>(x)[s * 32 + f4];
    float4 wv = reinterpret_cast<const float4*>(W)[f4];
    float* o = out + d * F_DIM + f4 * 4;
    unsafeAtomicAdd(o + 0, xv.x * wv.x * w);
    unsafeAtomicAdd(o + 1, xv.y * wv.y * w);
    unsafeAtomicAdd(o + 2, xv.z * wv.z * w);
    unsafeAtomicAdd(o + 3, xv.w * wv.w * w);
}

extern "C" void kernel_launch(void* const* d_in, const int* in_sizes, int n_in,
                              void* d_out, int out_size, void* d_ws, size_t ws_size,
                              hipStream_t stream)
{
    const float* x   = (const float*)d_in[0];
    const float* W   = (const float*)d_in[1];
    const float* ew  = (const float*)d_in[2];
    const int*   src = (const int*)d_in[3];
    const int*   dst = (const int*)d_in[4];
    float*       out = (float*)d_out;

    const int E  = in_sizes[2];
    const int N  = out_size / F_DIM;
    const int NU = N * 64;

    const int R = (N + NB - 1) / NB;                    // nodes per bucket
    int cap = (3 * E / (2 * NB) + 256) & ~255;          // ~1.5x mean, rounded
    if (cap < 512) cap = 512;
    const int cap2 = cap + 16 * R_MAX;                  // padded LDS cap
    const size_t smem_bytes = (size_t)cap2 * 6;         // f32 w + u16 src

    // ws layout (uint units): xb[NU] | segs[NB*cap*2] | g_cnt[NB]
    //   | spill_cnt[1] | align4 | spill[SPILL_CAP*4]
    size_t xb_off        = 0;
    size_t segs_off      = xb_off + (size_t)NU;
    size_t cnt_off       = segs_off + (size_t)NB * cap * 2;
    size_t spill_cnt_off = cnt_off + NB;
    size_t spill_off     = (spill_cnt_off + 1 + 3) & ~(size_t)3;
    size_t need          = (spill_off + (size_t)SPILL_CAP * 4) * 4;

    if (ws_size >= need && N >= 1 && N <= 16384 && R <= R_MAX &&
        cap <= 4096 && smem_bytes <= 64 * 1024) {
        unsigned* xb        = (unsigned*)d_ws + xb_off;
        uint2*    segs      = (uint2*)((unsigned*)d_ws + segs_off);
        int*      g_cnt     = (int*)d_ws + cnt_off;
        int*      spill_cnt = (int*)d_ws + spill_cnt_off;
        int4*     spill     = (int4*)((unsigned*)d_ws + spill_off);

        const unsigned M = (unsigned)((0x100000000ULL + R - 1) / (unsigned)R);

        int NU4    = NU / 4;
        int cgrid  = (NU4 + 255) / 256;
        int s1grid = (E + TILE - 1) / TILE;
        int bgrid  = (N + R - 1) / R;

        hipMemsetAsync(g_cnt, 0, (size_t)(NB + 1) * sizeof(int), stream);
        conv_sort1_kernel<<<cgrid + s1grid, 256, 0, stream>>>(
            x, W, xb, src, dst, ew, g_cnt, spill_cnt, spill, segs,
            NU4, cgrid, E, M, R, cap);
        bucket_kernel<<<bgrid, 1024, smem_bytes, stream>>>(
            xb, segs, g_cnt, spill_cnt, spill, out, N, R, cap, cap2);
    } else {
        hipMemsetAsync(out, 0, (size_t)out_size * sizeof(float), stream);
        long long tt = (long long)E * 32;
        int grid = (int)((tt + 255) / 256);
        if (grid < 1) grid = 1;
        fallback_scatter<<<grid, 256, 0, stream>>>(x, W, ew, src, dst, out, E);
    }
}

// Round 12
// 44.391 us; speedup vs baseline: 1.8015x; 1.0725x over previous
//
#include <hip/hip_runtime.h>

// GraphConvolutionDiagLayer: out[dst[e]] += ew[e] * (x[src[e]] * W)
// N=10000, E=640000, F=128, fp32.
//
// Round 12 (from R11's 47.6us = sort ~14 + bucket ~27 + memset/gaps ~6):
//  Gather is L2 LINE-THROUGHPUT bound (R3 fp32 rows: 2x lines = 2x time).
//  Floor ~20us. So: shave pad overhead (x8 not x16) and delete everything
//  else: NO global atomics, NO memset, NO spill path, 2 dispatches.
//   D1 conv_sort1: convert blocks (xb = pack2(bf16(x*W))) ++ sort blocks:
//      TILE=4096 edges -> LDS bucket-sort -> DENSE tile-contiguous record
//      dump to segs[tile*TILE ..] + tab[b][t] = off<<16|cnt (deterministic
//      offsets from the LDS scan -- replaces the g_cnt atomic reservation).
//   D2 bucket: per bucket: one-wave scan of tab row -> per-tile bases;
//      rounds of <=CAP_L records (1 round normally): 2-pass chunked read
//      (count, then place) into node-sorted LDS SoA (pad x8), then 16-wave
//      gather, batch-8 static dword row loads, register acc across rounds,
//      dense single write.
//  Fallback if ws/N/NT out of range.

#define F_DIM 128
#define NB 256
#define TILE 4096
#define SORT_T 512
#define NT_MAX 512
#define R_MAX 64
#define PADN 8
#define CAP_L 6144
#define CAP_LP (CAP_L + PADN * R_MAX)

__device__ __forceinline__ unsigned f2bf_bits(float f)
{
    unsigned u = __float_as_uint(f);
    return (u + 0x7FFFu + ((u >> 16) & 1u)) >> 16;   // RNE to bf16
}

__global__ void __launch_bounds__(SORT_T)
conv_sort1_kernel(const float* __restrict__ x, const float* __restrict__ W,
                  unsigned* __restrict__ xb,
                  const int* __restrict__ src, const int* __restrict__ dst,
                  const float* __restrict__ ew,
                  unsigned* __restrict__ tab, uint2* __restrict__ segs,
                  int NU4, int cgrid, int E, unsigned M, int R)
{
    __shared__ unsigned reo_lo[TILE];
    __shared__ unsigned reo_hi[TILE];
    __shared__ int hist[NB], scn[NB], wsum[8];

    int tid = threadIdx.x;

    if ((int)blockIdx.x < cgrid) {
        // ---------------- convert part ----------------
        int t = blockIdx.x * SORT_T + tid;
        if (t < NU4) {
            int n = t >> 4, jq = t & 15;
            const float4* xr = (const float4*)(x + (size_t)n * F_DIM + jq * 4);
            float4 a  = xr[0];
            float4 bb = xr[16];                 // +64 floats
            const float4* wr = (const float4*)(W + jq * 4);
            float4 wa = wr[0], wb = wr[16];
            uint4 o;
            o.x = f2bf_bits(a.x * wa.x) | (f2bf_bits(bb.x * wb.x) << 16);
            o.y = f2bf_bits(a.y * wa.y) | (f2bf_bits(bb.y * wb.y) << 16);
            o.z = f2bf_bits(a.z * wa.z) | (f2bf_bits(bb.z * wb.z) << 16);
            o.w = f2bf_bits(a.w * wa.w) | (f2bf_bits(bb.w * wb.w) << 16);
            *(uint4*)(xb + (size_t)n * 64 + jq * 4) = o;
        }
        return;
    }

    // ---------------- sort part ----------------
    int tile  = (int)blockIdx.x - cgrid;
    int tile0 = tile * TILE;
    int tcnt  = E - tile0; if (tcnt > TILE) tcnt = TILE;

    if (tid < NB) hist[tid] = 0;
    __syncthreads();

    int b_k[8], rank_k[8]; unsigned lo_k[8], w_k[8];
    #pragma unroll
    for (int k = 0; k < 8; ++k) {
        int e = tile0 + k * SORT_T + tid;
        b_k[k] = -1; rank_k[k] = 0; lo_k[k] = 0; w_k[k] = 0;
        if (e < E) {
            int d = dst[e];
            int b = (int)__umulhi((unsigned)d, M);     // d / R (exact)
            int dl = d - b * R;
            b_k[k]    = b;
            lo_k[k]   = ((unsigned)src[e] & 0x3FFFu) | ((unsigned)dl << 14)
                      | ((unsigned)b << 21);
            w_k[k]    = __float_as_uint(ew[e]);
            rank_k[k] = atomicAdd(&hist[b], 1);        // LDS int atomic
        }
    }
    __syncthreads();

    // wave-shuffle inclusive scan over NB=256 (first 4 of 8 waves)
    {
        int lane6 = tid & 63, wv = tid >> 6;
        int v = (tid < NB) ? hist[tid] : 0;
        #pragma unroll
        for (int d = 1; d < 64; d <<= 1) {
            int t2 = __shfl_up(v, d);
            if (lane6 >= d) v += t2;
        }
        if (lane6 == 63) wsum[wv] = v;
        __syncthreads();
        if (tid < NB) {
            int woff = 0;
            #pragma unroll
            for (int i2 = 0; i2 < 4; ++i2) if (i2 < wv) woff += wsum[i2];
            scn[tid] = v + woff;                       // inclusive scan
        }
        __syncthreads();
    }

    #pragma unroll
    for (int k = 0; k < 8; ++k) {
        if (b_k[k] >= 0) {
            int b = b_k[k];
            int pos = (scn[b] - hist[b]) + rank_k[k];  // excl offset + rank
            reo_lo[pos] = lo_k[k];
            reo_hi[pos] = w_k[k];
        }
    }
    __syncthreads();

    if (tid < NB)
        tab[(size_t)tid * NT_MAX + tile] =
            ((unsigned)(scn[tid] - hist[tid]) << 16) | (unsigned)hist[tid];

    for (int p = tid; p < tcnt; p += SORT_T)           // dense coalesced dump
        segs[(size_t)tile * TILE + p] = make_uint2(reo_lo[p], reo_hi[p]);
}

// One block per bucket, 1024 threads.
__global__ void __launch_bounds__(1024)
bucket_kernel(const unsigned* __restrict__ xb, const unsigned* __restrict__ tab,
              const uint2* __restrict__ segs, float* __restrict__ out,
              int N, int R, int NT)
{
    __shared__ __align__(16) float          w_l[CAP_LP];
    __shared__ __align__(16) unsigned short s_l[CAP_LP];
    __shared__ unsigned tbase_s[NT_MAX + 1], toff_s[NT_MAX];
    __shared__ int rstart[NT_MAX + 1];
    __shared__ int hist2[R_MAX], pexcl[R_MAX], cur[R_MAX];
    __shared__ int nrounds_s;

    int b   = blockIdx.x;
    int tid = threadIdx.x;
    int rows = N - b * R; if (rows > R) rows = R;
    if (rows <= 0) return;

    // phase A (wave 0): per-tile cumulative bases + round boundaries
    if (tid < 64) {
        int run = 0;
        for (int t0 = 0; t0 < NT; t0 += 64) {
            int t = t0 + tid;
            unsigned e = (t < NT) ? tab[(size_t)b * NT_MAX + t] : 0u;
            int c = (int)(e & 0xFFFFu);
            int v = c;
            #pragma unroll
            for (int d = 1; d < 64; d <<= 1) {
                int t2 = __shfl_up(v, d);
                if (tid >= d) v += t2;
            }
            if (t < NT) { tbase_s[t] = (unsigned)(run + v - c); toff_s[t] = e >> 16; }
            run += __shfl(v, 63);
        }
        if (tid == 0) {
            tbase_s[NT] = (unsigned)run;
            int nr = 0, base = 0;
            rstart[0] = 0;
            for (int t = 0; t < NT; ++t) {
                if ((int)tbase_s[t + 1] - base > CAP_L) {
                    base = (int)tbase_s[t];
                    rstart[++nr] = t;
                }
            }
            rstart[nr + 1] = NT;
            nrounds_s = nr + 1;
        }
    }
    __syncthreads();

    int wid = tid >> 6, lane = tid & 63;
    float acx[4], acy[4];
    #pragma unroll
    for (int j = 0; j < 4; ++j) { acx[j] = 0.f; acy[j] = 0.f; }

    int NR = nrounds_s;
    for (int rr = 0; rr < NR; ++rr) {
        int tA = rstart[rr], tB = rstart[rr + 1];

        if (tid < R_MAX) hist2[tid] = 0;
        __syncthreads();

        // pass 1: count per node
        for (int t = tA + wid; t < tB; t += 16) {
            int c_t = (int)(tbase_s[t + 1] - tbase_s[t]);
            const uint2* chunk = segs + (size_t)t * TILE + toff_s[t];
            for (int l = lane; l < c_t; l += 64)
                atomicAdd(&hist2[(chunk[l].x >> 14) & 0x7Fu], 1);
        }
        __syncthreads();

        // segment scan (pad x8)
        if (tid < 64) {
            int h = (tid < rows) ? hist2[tid] : 0;
            int p = (h + PADN - 1) & ~(PADN - 1);
            int v = p;
            #pragma unroll
            for (int d = 1; d < 64; d <<= 1) {
                int t2 = __shfl_up(v, d);
                if (tid >= d) v += t2;
            }
            if (tid < rows) { pexcl[tid] = v - p; cur[tid] = v - p; }
        }
        __syncthreads();

        // pass 2: place (chunks L2-hot from pass 1)
        for (int t = tA + wid; t < tB; t += 16) {
            int c_t = (int)(tbase_s[t + 1] - tbase_s[t]);
            const uint2* chunk = segs + (size_t)t * TILE + toff_s[t];
            for (int l = lane; l < c_t; l += 64) {
                uint2 q = chunk[l];
                int dl = (int)((q.x >> 14) & 0x7Fu);
                int pos = atomicAdd(&cur[dl], 1);      // LDS int atomic
                s_l[pos] = (unsigned short)(q.x & 0x3FFFu);
                w_l[pos] = __uint_as_float(q.y);
            }
        }
        __syncthreads();

        // zero-fill pads (w=0, src=0 -> no contribution)
        if (tid < rows) {
            int h = hist2[tid];
            int hp = (h + PADN - 1) & ~(PADN - 1);
            int bs = pexcl[tid];
            for (int p = bs + h; p < bs + hp; ++p) { s_l[p] = 0; w_l[p] = 0.f; }
        }
        __syncthreads();

        // gather: wave wid owns nodes wid, wid+16, wid+32, wid+48
        #pragma unroll
        for (int j = 0; j < 4; ++j) {
            int dl = wid + j * 16;
            if (dl < rows) {
                int hp = (hist2[dl] + PADN - 1) & ~(PADN - 1);
                int bs = pexcl[dl];
                float ax = acx[j], ay = acy[j];
                for (int i = 0; i < hp; i += 8) {
                    uint4 sa = *(const uint4*)(s_l + bs + i);
                    float4 wa = *(const float4*)(w_l + bs + i);
                    float4 wb = *(const float4*)(w_l + bs + i + 4);
                    unsigned sv[8] = {sa.x & 0xFFFFu, sa.x >> 16,
                                      sa.y & 0xFFFFu, sa.y >> 16,
                                      sa.z & 0xFFFFu, sa.z >> 16,
                                      sa.w & 0xFFFFu, sa.w >> 16};
                    float wv[8] = {wa.x, wa.y, wa.z, wa.w,
                                   wb.x, wb.y, wb.z, wb.w};
                    unsigned rv[8];
                    #pragma unroll
                    for (int k = 0; k < 8; ++k)
                        rv[k] = xb[(size_t)sv[k] * 64 + lane];
                    #pragma unroll
                    for (int k = 0; k < 8; ++k) {
                        ax += wv[k] * __uint_as_float(rv[k] << 16);
                        ay += wv[k] * __uint_as_float(rv[k] & 0xFFFF0000u);
                    }
                }
                acx[j] = ax; acy[j] = ay;
            }
        }
        __syncthreads();   // s_l/w_l reused next round
    }

    #pragma unroll
    for (int j = 0; j < 4; ++j) {
        int dl = wid + j * 16;
        if (dl < rows) {
            int n = b * R + dl;
            out[(size_t)n * F_DIM + lane]      = acx[j];
            out[(size_t)n * F_DIM + 64 + lane] = acy[j];
        }
    }
}

// ---- fallback: direct fp32 atomic scatter ----
__global__ void __launch_bounds__(256)
fallback_scatter(const float* __restrict__ x, const float* __restrict__ W,
                 const float* __restrict__ ew, const int* __restrict__ src,
                 const int* __restrict__ dst, float* __restrict__ out, int E)
{
    int t = blockIdx.x * 256 + threadIdx.x;
    int e = t >> 5;
    if (e >= E) return;
    int f4 = t & 31;
    int   s = src[e];
    int   d = dst[e];
    float w = ew[e];
    float4 xv = reinterpret_cast<const float4*>(x)[s * 32 + f4];
    float4 wv = reinterpret_cast<const float4*>(W)[f4];
    float* o = out + d * F_DIM + f4 * 4;
    unsafeAtomicAdd(o + 0, xv.x * wv.x * w);
    unsafeAtomicAdd(o + 1, xv.y * wv.y * w);
    unsafeAtomicAdd(o + 2, xv.z * wv.z * w);
    unsafeAtomicAdd(o + 3, xv.w * wv.w * w);
}

extern "C" void kernel_launch(void* const* d_in, const int* in_sizes, int n_in,
                              void* d_out, int out_size, void* d_ws, size_t ws_size,
                              hipStream_t stream)
{
    const float* x   = (const float*)d_in[0];
    const float* W   = (const float*)d_in[1];
    const float* ew  = (const float*)d_in[2];
    const int*   src = (const int*)d_in[3];
    const int*   dst = (const int*)d_in[4];
    float*       out = (float*)d_out;

    const int E  = in_sizes[2];
    const int N  = out_size / F_DIM;
    const int NU = N * 64;

    const int R  = (N + NB - 1) / NB;                  // nodes per bucket
    const int NT = (E + TILE - 1) / TILE;              // edge tiles

    // ws layout (uint units): xb[NU] | tab[NB*NT_MAX] | segs[NT*TILE*2]
    size_t xb_off   = 0;
    size_t tab_off  = xb_off + (size_t)NU;
    size_t segs_off = tab_off + (size_t)NB * NT_MAX;
    size_t need     = (segs_off + (size_t)NT * TILE * 2) * 4;

    if (ws_size >= need && N >= 1 && N <= 16384 && NT <= NT_MAX) {
        unsigned* xb   = (unsigned*)d_ws + xb_off;
        unsigned* tab  = (unsigned*)d_ws + tab_off;
        uint2*    segs = (uint2*)((unsigned*)d_ws + segs_off);

        const unsigned M = (unsigned)((0x100000000ULL + R - 1) / (unsigned)R);

        int NU4   = NU / 4;
        int cgrid = (NU4 + SORT_T - 1) / SORT_T;
        int bgrid = (N + R - 1) / R;

        conv_sort1_kernel<<<cgrid + NT, SORT_T, 0, stream>>>(
            x, W, xb, src, dst, ew, tab, segs, NU4, cgrid, E, M, R);
        bucket_kernel<<<bgrid, 1024, 0, stream>>>(xb, tab, segs, out, N, R, NT);
    } else {
        hipMemsetAsync(out, 0, (size_t)out_size * sizeof(float), stream);
        long long tt = (long long)E * 32;
        int grid = (int)((tt + 255) / 256);
        if (grid < 1) grid = 1;
        fallback_scatter<<<grid, 256, 0, stream>>>(x, W, ew, src, dst, out, E);
    }
}

// Round 13
// 36.614 us; speedup vs baseline: 2.1842x; 1.2124x over previous
//
#include <hip/hip_runtime.h>

// GraphConvolutionDiagLayer: out[dst[e]] += ew[e] * (x[src[e]] * W)
// N=10000, E=640000, F=128, fp32.
//
// Round 13 (from R12's 44.4us = sort ~14 + bucket ~27 + gaps ~3):
//  bucket has been ~27us across ALL variants while models say ~15 -> the
//  invariant is grid=250 (<256 CUs) = 1 block/CU: every barrier-phase's
//  latency is exposed serially, nothing co-resident to overlap it.
//   D1 conv_sort1: UNCHANGED from R12 (convert xb=pack2(bf16(x*W)) ++
//      TILE=4096 tile-sort -> dense tile-major records + tab[b][t]).
//   D2 bucket: 2 blocks PER BUCKET (grid=500, ~2/CU => cross-block phase
//      overlap). Block 2b+j owns half the bucket's nodes (NHALF<=32).
//      SINGLE streaming pass: records placed straight into fixed-stride
//      per-node LDS slots (cap 160 >> max degree ~98) via LDS cursors --
//      no count pass, no scan, no rounds. Pad x8, batch-8 gather (R12
//      inner, fully static), dense single write.
//      Overflow (P~1e-7): flag -> exact from-scratch broadcast re-stream.
//  Fallback if ws/N/NT out of range.

#define F_DIM 128
#define NB 256
#define TILE 4096
#define SORT_T 512
#define NT_MAX 512
#define NH_MAX 32
#define CAPC 160          // per-node LDS record cap (mult of 8)

__device__ __forceinline__ unsigned f2bf_bits(float f)
{
    unsigned u = __float_as_uint(f);
    return (u + 0x7FFFu + ((u >> 16) & 1u)) >> 16;   // RNE to bf16
}

__global__ void __launch_bounds__(SORT_T)
conv_sort1_kernel(const float* __restrict__ x, const float* __restrict__ W,
                  unsigned* __restrict__ xb,
                  const int* __restrict__ src, const int* __restrict__ dst,
                  const float* __restrict__ ew,
                  unsigned* __restrict__ tab, uint2* __restrict__ segs,
                  int NU4, int cgrid, int E, unsigned M, int R)
{
    __shared__ unsigned reo_lo[TILE];
    __shared__ unsigned reo_hi[TILE];
    __shared__ int hist[NB], scn[NB], wsum[8];

    int tid = threadIdx.x;

    if ((int)blockIdx.x < cgrid) {
        // ---------------- convert part ----------------
        int t = blockIdx.x * SORT_T + tid;
        if (t < NU4) {
            int n = t >> 4, jq = t & 15;
            const float4* xr = (const float4*)(x + (size_t)n * F_DIM + jq * 4);
            float4 a  = xr[0];
            float4 bb = xr[16];                 // +64 floats
            const float4* wr = (const float4*)(W + jq * 4);
            float4 wa = wr[0], wb = wr[16];
            uint4 o;
            o.x = f2bf_bits(a.x * wa.x) | (f2bf_bits(bb.x * wb.x) << 16);
            o.y = f2bf_bits(a.y * wa.y) | (f2bf_bits(bb.y * wb.y) << 16);
            o.z = f2bf_bits(a.z * wa.z) | (f2bf_bits(bb.z * wb.z) << 16);
            o.w = f2bf_bits(a.w * wa.w) | (f2bf_bits(bb.w * wb.w) << 16);
            *(uint4*)(xb + (size_t)n * 64 + jq * 4) = o;
        }
        return;
    }

    // ---------------- sort part ----------------
    int tile  = (int)blockIdx.x - cgrid;
    int tile0 = tile * TILE;
    int tcnt  = E - tile0; if (tcnt > TILE) tcnt = TILE;

    if (tid < NB) hist[tid] = 0;
    __syncthreads();

    int b_k[8], rank_k[8]; unsigned lo_k[8], w_k[8];
    #pragma unroll
    for (int k = 0; k < 8; ++k) {
        int e = tile0 + k * SORT_T + tid;
        b_k[k] = -1; rank_k[k] = 0; lo_k[k] = 0; w_k[k] = 0;
        if (e < E) {
            int d = dst[e];
            int b = (int)__umulhi((unsigned)d, M);     // d / R (exact)
            int dl = d - b * R;
            b_k[k]    = b;
            lo_k[k]   = ((unsigned)src[e] & 0x3FFFu) | ((unsigned)dl << 14)
                      | ((unsigned)b << 21);
            w_k[k]    = __float_as_uint(ew[e]);
            rank_k[k] = atomicAdd(&hist[b], 1);        // LDS int atomic
        }
    }
    __syncthreads();

    // wave-shuffle inclusive scan over NB=256 (first 4 of 8 waves)
    {
        int lane6 = tid & 63, wv = tid >> 6;
        int v = (tid < NB) ? hist[tid] : 0;
        #pragma unroll
        for (int d = 1; d < 64; d <<= 1) {
            int t2 = __shfl_up(v, d);
            if (lane6 >= d) v += t2;
        }
        if (lane6 == 63) wsum[wv] = v;
        __syncthreads();
        if (tid < NB) {
            int woff = 0;
            #pragma unroll
            for (int i2 = 0; i2 < 4; ++i2) if (i2 < wv) woff += wsum[i2];
            scn[tid] = v + woff;                       // inclusive scan
        }
        __syncthreads();
    }

    #pragma unroll
    for (int k = 0; k < 8; ++k) {
        if (b_k[k] >= 0) {
            int b = b_k[k];
            int pos = (scn[b] - hist[b]) + rank_k[k];  // excl offset + rank
            reo_lo[pos] = lo_k[k];
            reo_hi[pos] = w_k[k];
        }
    }
    __syncthreads();

    if (tid < NB)
        tab[(size_t)tid * NT_MAX + tile] =
            ((unsigned)(scn[tid] - hist[tid]) << 16) | (unsigned)hist[tid];

    for (int p = tid; p < tcnt; p += SORT_T)           // dense coalesced dump
        segs[(size_t)tile * TILE + p] = make_uint2(reo_lo[p], reo_hi[p]);
}

// Two blocks per bucket (block 2b+j owns nodes [j*NHALF, j*NHALF+nh) of
// bucket b), 512 threads. Single-pass placement into fixed-stride per-node
// LDS slots; batch-8 static gather; flag -> exact slow re-stream (never
// taken in practice).
__global__ void __launch_bounds__(512)
bucket_kernel(const unsigned* __restrict__ xb, const unsigned* __restrict__ tab,
              const uint2* __restrict__ segs, float* __restrict__ out,
              int N, int R, int NT)
{
    __shared__ __align__(16) float          w_l[NH_MAX * CAPC];  // 20.5KB
    __shared__ __align__(16) unsigned short s_l[NH_MAX * CAPC];  // 10.2KB
    __shared__ unsigned tabrow[NT_MAX];
    __shared__ int cur[NH_MAX];
    __shared__ int ovf_flag;

    int blk = blockIdx.x;
    int b   = blk >> 1;
    int jh  = blk & 1;
    int tid = threadIdx.x;

    int NHALF = (R + 1) >> 1;                       // <= NH_MAX (R <= 64)
    int brow0 = b * R;
    int rows  = N - brow0; if (rows > R) rows = R;
    if (rows <= 0) return;
    int nlo = jh * NHALF;                           // first local node
    int nh  = rows - nlo; if (nh > NHALF) nh = NHALF;
    if (nh <= 0) return;

    for (int t = tid; t < NT; t += 512) tabrow[t] = tab[(size_t)b * NT_MAX + t];
    if (tid < NH_MAX) cur[tid] = tid * CAPC;
    if (tid == 0) ovf_flag = 0;
    __syncthreads();

    int wid = tid >> 6, lane = tid & 63;

    // -------- single placement pass over this bucket's tile chunks --------
    for (int t = wid; t < NT; t += 8) {
        unsigned e = tabrow[t];
        int c_t = (int)(e & 0xFFFFu);
        const uint2* chunk = segs + (size_t)t * TILE + (e >> 16);
        for (int l = lane; l < c_t; l += 64) {
            uint2 q = chunk[l];
            int dll = (int)((q.x >> 14) & 0x7Fu) - nlo;
            if (dll >= 0 && dll < nh) {
                int pos = atomicAdd(&cur[dll], 1);  // LDS int atomic
                if (pos < dll * CAPC + CAPC) {
                    s_l[pos] = (unsigned short)(q.x & 0x3FFFu);
                    w_l[pos] = __uint_as_float(q.y);
                } else {
                    ovf_flag = 1;                   // same-value race OK
                }
            }
        }
    }
    __syncthreads();

    if (!ovf_flag) {
        // pad each node's tail to x8 (w=0, src=0 -> no contribution)
        if (tid < nh) {
            int cnt = cur[tid] - tid * CAPC;
            int hp  = (cnt + 7) & ~7;               // <= CAPC (CAPC%8==0)
            for (int p = tid * CAPC + cnt; p < tid * CAPC + hp; ++p) {
                s_l[p] = 0; w_l[p] = 0.f;
            }
        }
        __syncthreads();

        // -------- gather: wave wid owns local nodes wid, wid+8, ... --------
        #pragma unroll
        for (int j = 0; j < 4; ++j) {
            int dll = wid + j * 8;
            if (dll < nh) {
                int cnt = cur[dll] - dll * CAPC;
                int hp  = (cnt + 7) & ~7;
                int bs  = dll * CAPC;
                float ax = 0.f, ay = 0.f;
                for (int i = 0; i < hp; i += 8) {
                    uint4 sa = *(const uint4*)(s_l + bs + i);
                    float4 wa = *(const float4*)(w_l + bs + i);
                    float4 wb = *(const float4*)(w_l + bs + i + 4);
                    unsigned sv[8] = {sa.x & 0xFFFFu, sa.x >> 16,
                                      sa.y & 0xFFFFu, sa.y >> 16,
                                      sa.z & 0xFFFFu, sa.z >> 16,
                                      sa.w & 0xFFFFu, sa.w >> 16};
                    float wv[8] = {wa.x, wa.y, wa.z, wa.w,
                                   wb.x, wb.y, wb.z, wb.w};
                    unsigned rv[8];
                    #pragma unroll
                    for (int k = 0; k < 8; ++k)
                        rv[k] = xb[(size_t)sv[k] * 64 + lane];
                    #pragma unroll
                    for (int k = 0; k < 8; ++k) {
                        ax += wv[k] * __uint_as_float(rv[k] << 16);
                        ay += wv[k] * __uint_as_float(rv[k] & 0xFFFF0000u);
                    }
                }
                int n = brow0 + nlo + dll;
                out[(size_t)n * F_DIM + lane]      = ax;
                out[(size_t)n * F_DIM + 64 + lane] = ay;
            }
        }
    } else {
        // -------- exact slow path: from-scratch broadcast re-stream --------
        #pragma unroll
        for (int j = 0; j < 4; ++j) {
            int dll = wid + j * 8;
            if (dll < nh) {
                int dwant = dll + nlo;
                float ax = 0.f, ay = 0.f;
                for (int t = 0; t < NT; ++t) {
                    unsigned e = tabrow[t];
                    int c_t = (int)(e & 0xFFFFu);
                    const uint2* chunk = segs + (size_t)t * TILE + (e >> 16);
                    for (int l = 0; l < c_t; ++l) {
                        uint2 q = chunk[l];             // uniform broadcast
                        if ((int)((q.x >> 14) & 0x7Fu) == dwant) {
                            unsigned rv = xb[(size_t)(q.x & 0x3FFFu) * 64 + lane];
                            float w = __uint_as_float(q.y);
                            ax += w * __uint_as_float(rv << 16);
                            ay += w * __uint_as_float(rv & 0xFFFF0000u);
                        }
                    }
                }
                int n = brow0 + nlo + dll;
                out[(size_t)n * F_DIM + lane]      = ax;
                out[(size_t)n * F_DIM + 64 + lane] = ay;
            }
        }
    }
}

// ---- fallback: direct fp32 atomic scatter ----
__global__ void __launch_bounds__(256)
fallback_scatter(const float* __restrict__ x, const float* __restrict__ W,
                 const float* __restrict__ ew, const int* __restrict__ src,
                 const int* __restrict__ dst, float* __restrict__ out, int E)
{
    int t = blockIdx.x * 256 + threadIdx.x;
    int e = t >> 5;
    if (e >= E) return;
    int f4 = t & 31;
    int   s = src[e];
    int   d = dst[e];
    float w = ew[e];
    float4 xv = reinterpret_cast<const float4*>(x)[s * 32 + f4];
    float4 wv = reinterpret_cast<const float4*>(W)[f4];
    float* o = out + d * F_DIM + f4 * 4;
    unsafeAtomicAdd(o + 0, xv.x * wv.x * w);
    unsafeAtomicAdd(o + 1, xv.y * wv.y * w);
    unsafeAtomicAdd(o + 2, xv.z * wv.z * w);
    unsafeAtomicAdd(o + 3, xv.w * wv.w * w);
}

extern "C" void kernel_launch(void* const* d_in, const int* in_sizes, int n_in,
                              void* d_out, int out_size, void* d_ws, size_t ws_size,
                              hipStream_t stream)
{
    const float* x   = (const float*)d_in[0];
    const float* W   = (const float*)d_in[1];
    const float* ew  = (const float*)d_in[2];
    const int*   src = (const int*)d_in[3];
    const int*   dst = (const int*)d_in[4];
    float*       out = (float*)d_out;

    const int E  = in_sizes[2];
    const int N  = out_size / F_DIM;
    const int NU = N * 64;

    const int R  = (N + NB - 1) / NB;                  // nodes per bucket
    const int NT = (E + TILE - 1) / TILE;              // edge tiles

    // ws layout (uint units): xb[NU] | tab[NB*NT_MAX] | segs[NT*TILE*2]
    size_t xb_off   = 0;
    size_t tab_off  = xb_off + (size_t)NU;
    size_t segs_off = tab_off + (size_t)NB * NT_MAX;
    size_t need     = (segs_off + (size_t)NT * TILE * 2) * 4;

    if (ws_size >= need && N >= 1 && N <= 16384 && NT <= NT_MAX && R <= 64) {
        unsigned* xb   = (unsigned*)d_ws + xb_off;
        unsigned* tab  = (unsigned*)d_ws + tab_off;
        uint2*    segs = (uint2*)((unsigned*)d_ws + segs_off);

        const unsigned M = (unsigned)((0x100000000ULL + R - 1) / (unsigned)R);

        int NU4    = NU / 4;
        int cgrid  = (NU4 + SORT_T - 1) / SORT_T;
        int nbuck  = (N + R - 1) / R;
        int bgrid  = 2 * nbuck;

        conv_sort1_kernel<<<cgrid + NT, SORT_T, 0, stream>>>(
            x, W, xb, src, dst, ew, tab, segs, NU4, cgrid, E, M, R);
        bucket_kernel<<<bgrid, 512, 0, stream>>>(xb, tab, segs, out, N, R, NT);
    } else {
        hipMemsetAsync(out, 0, (size_t)out_size * sizeof(float), stream);
        long long tt = (long long)E * 32;
        int grid = (int)((tt + 255) / 256);
        if (grid < 1) grid = 1;
        fallback_scatter<<<grid, 256, 0, stream>>>(x, W, ew, src, dst, out, E);
    }
}